// Round 4
// baseline (418.176 us; speedup 1.0000x reference)
//
#include <hip/hip_runtime.h>
#include <math.h>

#define NPIX 4096

// ---------------- workspace layout (floats) ----------------
#define W_POS   0
#define W_SN    12288
#define W_MT    24576   // 144 used, 160 reserved
#define W_OUTS  24736
#define W_PN    37024
#define W_PB    49312   // ---- zero region start ----
#define W_QKV   61600
#define W_OP    73888
#define W_OUTP  86176
#define W_MOM   98464   // 34 used, 40 reserved
#define W_BAR   98504   // 16 ints (zeroed via hipMemsetAsync)
#define NZERO4  12298   // (W_MOM+40 - W_PB)/4 float4s to zero

// monomial composition tables (deg-k monomial + e_j -> deg-(k+1) index)
__device__ const int dT12[9]  = {0,1,2, 1,3,4, 2,4,5};
__device__ const int dT23[18] = {0,1,2, 1,3,4, 2,4,5, 3,6,7, 4,7,8, 5,8,9};
__device__ const int dT34[30] = {0,1,2, 1,3,4, 2,4,5, 3,6,7, 4,7,8, 5,8,9,
                                 6,10,11, 7,11,12, 8,12,13, 9,13,14};
__device__ const float dC2[6]  = {1,2,2,1,2,1};
__device__ const float dC3[10] = {1,3,3,3,6,3,1,3,3,1};
__device__ const float dC4[15] = {1,4,4,6,12,6,4,12,12,4,1,4,6,4,1};

__device__ __forceinline__ float gelu_exact(float x) {
    return 0.5f * x * (1.0f + erff(x * 0.70710678118654752440f));
}

__device__ __forceinline__ float conv3_tap(const float* __restrict__ src,
                                           const float* __restrict__ w,
                                           int o, int y, int x) {
    float acc = 0.f;
#pragma unroll
    for (int ci = 0; ci < 3; ++ci) {
#pragma unroll
        for (int dy = 0; dy < 3; ++dy) {
            int yy = y + dy - 1;
            if (yy < 0 || yy >= 64) continue;
#pragma unroll
            for (int dx = 0; dx < 3; ++dx) {
                int xx = x + dx - 1;
                if (xx < 0 || xx >= 64) continue;
                acc = fmaf(src[ci*NPIX + yy*64 + xx], w[o*27 + ci*9 + dy*3 + dx], acc);
            }
        }
    }
    return acc;
}

// all 34 monomials of (a0,a1,a2), degree 1..4, fixed ordering
__device__ __forceinline__ void build34(float a0, float a1, float a2, float* A) {
    A[0]=a0; A[1]=a1; A[2]=a2;
    A[3]=a0*a0; A[4]=a0*a1; A[5]=a0*a2; A[6]=a1*a1; A[7]=a1*a2; A[8]=a2*a2;
    A[9]=A[3]*a0; A[10]=A[3]*a1; A[11]=A[3]*a2; A[12]=A[4]*a1; A[13]=A[4]*a2;
    A[14]=A[5]*a2; A[15]=A[6]*a1; A[16]=A[6]*a2; A[17]=A[7]*a2; A[18]=A[8]*a2;
    A[19]=A[9]*a0; A[20]=A[9]*a1; A[21]=A[9]*a2; A[22]=A[10]*a1; A[23]=A[10]*a2;
    A[24]=A[11]*a2; A[25]=A[12]*a1; A[26]=A[12]*a2; A[27]=A[13]*a2; A[28]=A[14]*a2;
    A[29]=A[15]*a1; A[30]=A[15]*a2; A[31]=A[16]*a2; A[32]=A[17]*a2; A[33]=A[18]*a2;
}

// device-scope grid barrier (all gridDim.x blocks participate)
__device__ __forceinline__ void gbar(int* bar, int idx) {
    __syncthreads();
    if (threadIdx.x == 0) {
        __threadfence();   // release (agent scope, incl. cache ops)
        __hip_atomic_fetch_add(&bar[idx], 1, __ATOMIC_ACQ_REL, __HIP_MEMORY_SCOPE_AGENT);
        while (__hip_atomic_load(&bar[idx], __ATOMIC_ACQUIRE, __HIP_MEMORY_SCOPE_AGENT)
               < (int)gridDim.x)
            __builtin_amdgcn_s_sleep(2);
        __threadfence();   // acquire
    }
    __syncthreads();
}

__global__ __launch_bounds__(256) void fused_dam(
        const float* __restrict__ x,   const float* __restrict__ pew1,
        const float* __restrict__ pew2,
        const float* __restrict__ ew,  const float* __restrict__ eb,
        const float* __restrict__ g1,  const float* __restrict__ b1,
        const float* __restrict__ qpw, const float* __restrict__ ppw,
        const float* __restrict__ ppb, const float* __restrict__ rw,
        const float* __restrict__ rb,  const float* __restrict__ g2,
        const float* __restrict__ b2,  const float* __restrict__ qsw,
        const float* __restrict__ psw, const float* __restrict__ psb,
        const float* __restrict__ pdw1,const float* __restrict__ pdw2,
        float* __restrict__ ws, float* __restrict__ out) {
    __shared__ float smem[4608];
    const int b = blockIdx.x, tid = threadIdx.x;

    float* pos  = ws + W_POS;
    float* sn   = ws + W_SN;
    float* MT   = ws + W_MT;
    float* outs = ws + W_OUTS;
    float* pn   = ws + W_PN;
    float* pb   = ws + W_PB;
    float* qkvp = ws + W_QKV;
    float* op   = ws + W_OP;
    float* outp = ws + W_OUTP;
    float* mom  = ws + W_MOM;
    int*   bar  = (int*)(ws + W_BAR);

    // ================= P1: front conv+LN | MT | zero+warm =================
    if (b < 16) {
        float (*t1l)[8][64] = (float(*)[8][64])smem;
        int y0 = b * 4;
        for (int i = tid; i < 1536; i += 256) {
            int c = i >> 9, rr = (i >> 6) & 7, xx = i & 63;
            int yg = y0 - 2 + rr;
            float v = 0.f;
            if (yg >= 0 && yg < 64) v = gelu_exact(conv3_tap(x, pew1, c, yg, xx));
            t1l[c][rr][xx] = v;
        }
        __syncthreads();
        int n = b*256 + tid;
        int yl = tid >> 6, xx = tid & 63;
        int yg = y0 + yl;
        float p[3];
#pragma unroll
        for (int o = 0; o < 3; ++o) {
            float acc = 0.f;
#pragma unroll
            for (int ci = 0; ci < 3; ++ci) {
#pragma unroll
                for (int dy = 0; dy < 3; ++dy) {
                    int yy = yg + dy - 1;
                    if (yy < 0 || yy >= 64) continue;
                    int rl = yl + dy + 1;
#pragma unroll
                    for (int dx = 0; dx < 3; ++dx) {
                        int xc = xx + dx - 1;
                        if (xc < 0 || xc >= 64) continue;
                        acc = fmaf(t1l[ci][rl][xc], pew2[o*27 + ci*9 + dy*3 + dx], acc);
                    }
                }
            }
            p[o] = acc;
        }
        float mu = (p[0] + p[1] + p[2]) * (1.f/3.f);
        float d0 = p[0]-mu, d1 = p[1]-mu, d2 = p[2]-mu;
        float r = rsqrtf((d0*d0 + d1*d1 + d2*d2) * (1.f/3.f) + 1e-5f);
        pos[n] = p[0]; pos[NPIX+n] = p[1]; pos[2*NPIX+n] = p[2];
        sn[n]        = d0*r*g2[0] + b2[0];
        sn[NPIX+n]   = d1*r*g2[1] + b2[1];
        sn[2*NPIX+n] = d2*r*g2[2] + b2[2];
    } else if (b == 16) {
        if (tid < 144) {
            int isT = tid >= 72;
            int u = isT ? tid - 72 : tid;
            int h = u / 9, i = (u % 9) / 3, j = u % 3;
            float acc = 0.f;
            if (!isT) {   // M_h = Wq_h Wk_h^T / sqrt(32)  (natural scale)
                const float* wq = qsw + i*768 + h*32;
                const float* wk = qsw + j*768 + 256 + h*32;
#pragma unroll
                for (int d = 0; d < 32; ++d) acc = fmaf(wq[d], wk[d], acc);
                acc *= 0.17677669529663687f;
            } else {      // T_h = Wv_h Pr_h
                const float* wv = qsw + i*768 + 512 + h*32;
#pragma unroll
                for (int d = 0; d < 32; ++d) acc = fmaf(wv[d], psw[(h*32 + d)*3 + j], acc);
            }
            MT[tid] = acc;
        }
    } else {
        // zero atomic accumulators + warm L3 with weights
        int gid = (b - 17)*256 + tid;                 // 0..61183
        if (gid < NZERO4) ((float4*)(ws + W_PB))[gid] = make_float4(0.f,0.f,0.f,0.f);
        float acc = 0.f;
        for (int i = gid; i < 147456; i += 61184) { float4 v = ((const float4*)ew)[i];  acc += v.x+v.y+v.z+v.w; }
        for (int i = gid; i < 147456; i += 61184) { float4 v = ((const float4*)qpw)[i]; acc += v.x+v.y+v.z+v.w; }
        for (int i = gid; i < 49152;  i += 61184) { float4 v = ((const float4*)ppw)[i]; acc += v.x+v.y+v.z+v.w; }
        for (int i = gid; i < 147456; i += 61184) { float4 v = ((const float4*)rw)[i];  acc += v.x+v.y+v.z+v.w; }
        asm volatile("" :: "v"(acc));
    }
    gbar(bar, 0);

    // ================= P2: patch embed (24 blk) | moments (16 blk) =========
    if (b < 24) {
        int och = b % 3, ks = b / 3;       // 8 k-splits of 96
        int k0 = ks * 96;
        float* pv = smem;                  // [16][96]
        for (int idx = tid; idx < 1536; idx += 256) {
            int t = idx / 96, k = idx % 96;
            int kk = k0 + k;
            int cc = kk >> 8, pp = (kk >> 4) & 15, q = kk & 15;
            int hp = t >> 2, wp = t & 3;
            pv[idx] = pos[cc*NPIX + (hp*16 + pp)*64 + wp*16 + q];
        }
        __syncthreads();
        int o = och*256 + tid;
        float acc[16];
#pragma unroll
        for (int t = 0; t < 16; ++t) acc[t] = 0.f;
        const float4* wr = (const float4*)(ew + o*768 + k0);
#pragma unroll 2
        for (int k4 = 0; k4 < 24; ++k4) {
            float4 w4 = wr[k4];
#pragma unroll
            for (int t = 0; t < 16; ++t) {
                const float* p4 = &pv[t*96 + k4*4];
                acc[t] = fmaf(w4.x, p4[0], acc[t]);
                acc[t] = fmaf(w4.y, p4[1], acc[t]);
                acc[t] = fmaf(w4.z, p4[2], acc[t]);
                acc[t] = fmaf(w4.w, p4[3], acc[t]);
            }
        }
#pragma unroll
        for (int t = 0; t < 16; ++t) atomicAdd(&pb[t*768 + o], acc[t]);
    } else if (b < 40) {
        // moments of sn: 34 monomial sums over 4096 pixels
        int n = (b - 24)*256 + tid;
        float B[34];
        build34(sn[n], sn[NPIX+n], sn[2*NPIX+n], B);
        int lane = tid & 63, wid = tid >> 6;
#pragma unroll
        for (int u = 0; u < 34; ++u) {
            float t = B[u];
#pragma unroll
            for (int o = 1; o <= 32; o <<= 1) t += __shfl_xor(t, o);
            if (lane == 0) smem[wid*34 + u] = t;
        }
        __syncthreads();
        if (tid < 34)
            atomicAdd(&mom[tid], smem[tid] + smem[34+tid] + smem[68+tid] + smem[102+tid]);
    }
    gbar(bar, 1);

    // ================= P3: LN1 (16 blk) | pixel-attn poly eval (16 blk) ====
    if (b < 16) {
        int t = b;
        int base = t*768 + tid*3;
        float v0 = pb[base] + eb[tid*3], v1 = pb[base+1] + eb[tid*3+1],
              v2 = pb[base+2] + eb[tid*3+2];
        float s = v0+v1+v2, s2 = v0*v0+v1*v1+v2*v2;
#pragma unroll
        for (int o = 1; o <= 32; o <<= 1) { s += __shfl_xor(s, o); s2 += __shfl_xor(s2, o); }
        int wid = tid >> 6;
        if ((tid & 63) == 0) { smem[wid] = s; smem[4+wid] = s2; }
        __syncthreads();
        if (tid == 0) {
            float S = smem[0]+smem[1]+smem[2]+smem[3];
            float S2 = smem[4]+smem[5]+smem[6]+smem[7];
            float mu = S * (1.f/768.f);
            smem[8] = mu;
            smem[9] = rsqrtf(fmaxf(S2 * (1.f/768.f) - mu*mu, 0.f) + 1e-5f);
        }
        __syncthreads();
        float mu = smem[8], rs = smem[9];
        pn[base]   = (v0-mu)*rs*g1[tid*3]   + b1[tid*3];
        pn[base+1] = (v1-mu)*rs*g1[tid*3+1] + b1[tid*3+1];
        pn[base+2] = (v2-mu)*rs*g1[tid*3+2] + b1[tid*3+2];
    } else if (b < 32) {
        float* evmt = smem;          // 144
        float* evDW = smem + 144;    // 34
        float* evNW = smem + 180;    // 60  (3 x 20)
        if (tid < 144) evmt[tid] = MT[tid];        // FIX: full 144-entry load
        if (tid < 34) {
            float c;
            if (tid < 3) c = 1.f;
            else if (tid < 9)  c = dC2[tid-3]  * 0.5f;
            else if (tid < 19) c = dC3[tid-9]  * (1.f/6.f);
            else               c = dC4[tid-19] * (1.f/24.f);
            evDW[tid] = c * mom[tid];
        }
        if (tid >= 192 && tid < 252) {
            int q = tid - 192; int j = q / 20, u = q % 20;
            float val;
            if (u == 0)       val = mom[j];
            else if (u < 4)   val = mom[3  + dT12[(u-1)*3 + j]];
            else if (u < 10)  val = (dC2[u-4]  * 0.5f)      * mom[9  + dT23[(u-4)*3 + j]];
            else              val = (dC3[u-10] * (1.f/6.f)) * mom[19 + dT34[(u-10)*3 + j]];
            evNW[j*20 + u] = val;
        }
        __syncthreads();
        int n = (b-16)*256 + tid;
        float x0 = sn[n], x1 = sn[NPIX+n], x2 = sn[2*NPIX+n];
        float o0 = 0.f, o1 = 0.f, o2 = 0.f;
        for (int h = 0; h < 8; ++h) {
            const float* M = &evmt[h*9];
            float a0 = x0*M[0] + x1*M[3] + x2*M[6];
            float a1 = x0*M[1] + x1*M[4] + x2*M[7];
            float a2 = x0*M[2] + x1*M[5] + x2*M[8];
            float A[34];
            build34(a0, a1, a2, A);
            float den = 4096.f;
#pragma unroll
            for (int u = 0; u < 34; ++u) den = fmaf(A[u], evDW[u], den);
            float num[3];
#pragma unroll
            for (int j = 0; j < 3; ++j) {
                float s = evNW[j*20];
#pragma unroll
                for (int u = 0; u < 19; ++u) s = fmaf(A[u], evNW[j*20 + 1 + u], s);
                num[j] = s;
            }
            float ir = 1.f / den;
            float r0 = num[0]*ir, r1 = num[1]*ir, r2 = num[2]*ir;
            const float* T = &evmt[72 + h*9];
            o0 += r0*T[0] + r1*T[3] + r2*T[6];
            o1 += r0*T[1] + r1*T[4] + r2*T[7];
            o2 += r0*T[2] + r1*T[5] + r2*T[8];
        }
        outs[n]        = o0 + psb[0];
        outs[NPIX+n]   = o1 + psb[1];
        outs[2*NPIX+n] = o2 + psb[2];
    }
    gbar(bar, 2);

    // ================= P4: qkv_patch GEMM (24 blk) =========================
    if (b < 24) {
        int och = b % 3, ks = b / 3;     // 8 k-splits of 96
        int k0 = ks * 96;
        float* ps = smem;                // [16][96]
        for (int idx = tid; idx < 1536; idx += 256) {
            int t = idx / 96, k = idx % 96;
            ps[idx] = pn[t*768 + k0 + k];
        }
        __syncthreads();
        int o = och*256 + tid;
        float acc[16];
#pragma unroll
        for (int t = 0; t < 16; ++t) acc[t] = 0.f;
#pragma unroll 4
        for (int k = 0; k < 96; ++k) {
            float w = qpw[(k0 + k)*768 + o];
#pragma unroll
            for (int t = 0; t < 16; ++t) acc[t] = fmaf(ps[t*96 + k], w, acc[t]);
        }
#pragma unroll
        for (int t = 0; t < 16; ++t) atomicAdd(&qkvp[t*768 + o], acc[t]);
    }
    gbar(bar, 3);

    // ================= P5: patch attention + proj (12 blk) =================
    if (b < 12) {
        float* qsl = smem;            // 1024
        float* ksl = smem + 1024;
        float* vsl = smem + 2048;
        float* att = smem + 3072;     // 1024
        float* scl = smem + 4096;     // 512
        int och = b % 3, ks = b / 3;  // 4 head-pair slices of 64
        for (int idx = tid; idx < 1024; idx += 256) {
            int t = idx >> 6, j = idx & 63;
            qsl[idx] = qkvp[t*768 + ks*64 + j];
            ksl[idx] = qkvp[t*768 + 256 + ks*64 + j];
            vsl[idx] = qkvp[t*768 + 512 + ks*64 + j];
        }
        __syncthreads();
#pragma unroll
        for (int r = 0; r < 2; ++r) {
            int sidx = tid*2 + r;
            int hh = sidx >> 8, nn = (sidx >> 4) & 15, m = sidx & 15;
            float d = 0.f;
            const float* q = &qsl[nn*64 + hh*32];
            const float* k = &ksl[m*64 + hh*32];
#pragma unroll
            for (int dd = 0; dd < 32; ++dd) d = fmaf(q[dd], k[dd], d);
            scl[sidx] = d * 0.17677669529663687f;
        }
        __syncthreads();
        if (tid < 32) {
            int hh = tid >> 4, nn = tid & 15;
            float* row = &scl[hh*256 + nn*16];
            float mx = row[0];
#pragma unroll
            for (int m = 1; m < 16; ++m) mx = fmaxf(mx, row[m]);
            float s = 0.f;
#pragma unroll
            for (int m = 0; m < 16; ++m) { float e = expf(row[m]-mx); row[m] = e; s += e; }
            float inv = 1.f / s;
#pragma unroll
            for (int m = 0; m < 16; ++m) row[m] *= inv;
        }
        __syncthreads();
        {
            int j = tid & 63, ng = tid >> 6;
            int hh = j >> 5;
#pragma unroll
            for (int nn = ng*4; nn < ng*4 + 4; ++nn) {
                float a = 0.f;
#pragma unroll
                for (int m = 0; m < 16; ++m)
                    a = fmaf(scl[hh*256 + nn*16 + m], vsl[m*64 + j], a);
                att[nn*64 + j] = a;
            }
        }
        __syncthreads();
        int o = och*256 + tid;
        float acc[16];
#pragma unroll
        for (int t = 0; t < 16; ++t) acc[t] = 0.f;
#pragma unroll 4
        for (int k = 0; k < 64; ++k) {
            float w = ppw[(ks*64 + k)*768 + o];
#pragma unroll
            for (int t = 0; t < 16; ++t) acc[t] = fmaf(att[t*64 + k], w, acc[t]);
        }
#pragma unroll
        for (int t = 0; t < 16; ++t) atomicAdd(&op[t*768 + o], acc[t]);
    }
    gbar(bar, 4);

    // ================= P6: recon conv-transpose (24 blk) ===================
    if (b < 24) {
        int dch = b % 3, cs = b / 3;   // 8 c-splits of 96
        int c0 = cs * 96;
        float* os_ = smem;             // [16][96]
        for (int idx = tid; idx < 1536; idx += 256) {
            int t = idx / 96, k = idx % 96;
            os_[idx] = op[t*768 + c0 + k] + ppb[c0 + k];
        }
        __syncthreads();
        int dij = dch*256 + tid;
        float acc[16];
#pragma unroll
        for (int t = 0; t < 16; ++t) acc[t] = 0.f;
#pragma unroll 4
        for (int k = 0; k < 96; ++k) {
            float w = rw[(c0 + k)*768 + dij];
#pragma unroll
            for (int t = 0; t < 16; ++t) acc[t] = fmaf(os_[t*96 + k], w, acc[t]);
        }
        int d = dij >> 8, i = (dij >> 4) & 15, j = dij & 15;
#pragma unroll
        for (int t = 0; t < 16; ++t) {
            int hp = t >> 2, wp = t & 3;
            atomicAdd(&outp[d*NPIX + (hp*16 + i)*64 + wp*16 + j], acc[t]);
        }
    }
    gbar(bar, 5);

    // ================= P7: combine + final convs ===========================
    if (b < 16) {
        float (*t2l)[8][64] = (float(*)[8][64])smem;
        int y0 = b * 4;
        for (int i = tid; i < 1536; i += 256) {
            int c = i >> 9, rr = (i >> 6) & 7, xx = i & 63;
            int yg = y0 - 2 + rr;
            float v = 0.f;
            if (yg >= 0 && yg < 64) {
                float acc = 0.f;
#pragma unroll
                for (int ci = 0; ci < 3; ++ci) {
                    float bias = rb[ci];
#pragma unroll
                    for (int dy = 0; dy < 3; ++dy) {
                        int yy = yg + dy - 1;
                        if (yy < 0 || yy >= 64) continue;
#pragma unroll
                        for (int dx = 0; dx < 3; ++dx) {
                            int xc = xx + dx - 1;
                            if (xc < 0 || xc >= 64) continue;
                            float cb = outp[ci*NPIX + yy*64 + xc] + bias
                                     + outs[ci*NPIX + yy*64 + xc];
                            acc = fmaf(cb, pdw1[c*27 + ci*9 + dy*3 + dx], acc);
                        }
                    }
                }
                v = gelu_exact(acc);
            }
            t2l[c][rr][xx] = v;
        }
        __syncthreads();
        int yl = tid >> 6, xx = tid & 63;
        int yg = y0 + yl;
#pragma unroll
        for (int o = 0; o < 3; ++o) {
            float acc = 0.f;
#pragma unroll
            for (int ci = 0; ci < 3; ++ci) {
#pragma unroll
                for (int dy = 0; dy < 3; ++dy) {
                    int yy = yg + dy - 1;
                    if (yy < 0 || yy >= 64) continue;
                    int rl = yl + dy + 1;
#pragma unroll
                    for (int dx = 0; dx < 3; ++dx) {
                        int xc = xx + dx - 1;
                        if (xc < 0 || xc >= 64) continue;
                        acc = fmaf(t2l[ci][rl][xc], pdw2[o*27 + ci*9 + dy*3 + dx], acc);
                    }
                }
            }
            out[o*NPIX + yg*64 + xx] = acc;
        }
    }
}

extern "C" void kernel_launch(void* const* d_in, const int* in_sizes, int n_in,
                              void* d_out, int out_size, void* d_ws, size_t ws_size,
                              hipStream_t stream) {
    (void)in_sizes; (void)n_in; (void)out_size; (void)ws_size;
    const float* x    = (const float*)d_in[0];
    const float* pew1 = (const float*)d_in[1];
    const float* pew2 = (const float*)d_in[2];
    const float* ew   = (const float*)d_in[3];
    const float* eb   = (const float*)d_in[4];
    const float* g1   = (const float*)d_in[5];
    const float* b1   = (const float*)d_in[6];
    const float* qpw  = (const float*)d_in[7];
    const float* ppw  = (const float*)d_in[8];
    const float* ppb  = (const float*)d_in[9];
    const float* rw   = (const float*)d_in[10];
    const float* rb   = (const float*)d_in[11];
    const float* g2   = (const float*)d_in[12];
    const float* b2   = (const float*)d_in[13];
    const float* qsw  = (const float*)d_in[14];
    const float* psw  = (const float*)d_in[15];
    const float* psb  = (const float*)d_in[16];
    const float* pdw1 = (const float*)d_in[17];
    const float* pdw2 = (const float*)d_in[18];

    float* ws  = (float*)d_ws;
    float* out = (float*)d_out;

    hipMemsetAsync((char*)d_ws + (size_t)W_BAR*4, 0, 64, stream);
    fused_dam<<<dim3(256), dim3(256), 0, stream>>>(
        x, pew1, pew2, ew, eb, g1, b1, qpw, ppw, ppb, rw, rb, g2, b2,
        qsw, psw, psb, pdw1, pdw2, ws, out);
}

// Round 6
// 219.041 us; speedup vs baseline: 1.9091x; 1.9091x over previous
//
#include <hip/hip_runtime.h>
#include <math.h>

#define NPIX 4096
#define AG __HIP_MEMORY_SCOPE_AGENT

// ---------------- workspace layout (floats) ----------------
#define W_POS   0
#define W_SN    12288
#define W_MT    24576   // 144 used, 160 reserved
#define W_OUTS  24736
#define W_PN    37024
#define W_PB    49312   // ---- zero region start ----
#define W_QKV   61600
#define W_OP    73888
#define W_OUTP  86176
#define W_MOM   98464   // 34 used, 40 reserved
#define W_BAR   98504   // 16 ints (zeroed via hipMemsetAsync)
#define NZERO   49192   // floats to zero: W_PB .. W_MOM+40

// monomial composition tables (deg-k monomial + e_j -> deg-(k+1) index)
__device__ const int dT12[9]  = {0,1,2, 1,3,4, 2,4,5};
__device__ const int dT23[18] = {0,1,2, 1,3,4, 2,4,5, 3,6,7, 4,7,8, 5,8,9};
__device__ const int dT34[30] = {0,1,2, 1,3,4, 2,4,5, 3,6,7, 4,7,8, 5,8,9,
                                 6,10,11, 7,11,12, 8,12,13, 9,13,14};
__device__ const float dC2[6]  = {1,2,2,1,2,1};
__device__ const float dC3[10] = {1,3,3,3,6,3,1,3,3,1};
__device__ const float dC4[15] = {1,4,4,6,12,6,4,12,12,4,1,4,6,4,1};

__device__ __forceinline__ float gelu_exact(float x) {
    return 0.5f * x * (1.0f + erff(x * 0.70710678118654752440f));
}

__device__ __forceinline__ float conv3_tap(const float* __restrict__ src,
                                           const float* __restrict__ w,
                                           int o, int y, int x) {
    float acc = 0.f;
#pragma unroll
    for (int ci = 0; ci < 3; ++ci) {
#pragma unroll
        for (int dy = 0; dy < 3; ++dy) {
            int yy = y + dy - 1;
            if (yy < 0 || yy >= 64) continue;
#pragma unroll
            for (int dx = 0; dx < 3; ++dx) {
                int xx = x + dx - 1;
                if (xx < 0 || xx >= 64) continue;
                acc = fmaf(src[ci*NPIX + yy*64 + xx], w[o*27 + ci*9 + dy*3 + dx], acc);
            }
        }
    }
    return acc;
}

// all 34 monomials of (a0,a1,a2), degree 1..4, fixed ordering
__device__ __forceinline__ void build34(float a0, float a1, float a2, float* A) {
    A[0]=a0; A[1]=a1; A[2]=a2;
    A[3]=a0*a0; A[4]=a0*a1; A[5]=a0*a2; A[6]=a1*a1; A[7]=a1*a2; A[8]=a2*a2;
    A[9]=A[3]*a0; A[10]=A[3]*a1; A[11]=A[3]*a2; A[12]=A[4]*a1; A[13]=A[4]*a2;
    A[14]=A[5]*a2; A[15]=A[6]*a1; A[16]=A[6]*a2; A[17]=A[7]*a2; A[18]=A[8]*a2;
    A[19]=A[9]*a0; A[20]=A[9]*a1; A[21]=A[9]*a2; A[22]=A[10]*a1; A[23]=A[10]*a2;
    A[24]=A[11]*a2; A[25]=A[12]*a1; A[26]=A[12]*a2; A[27]=A[13]*a2; A[28]=A[14]*a2;
    A[29]=A[15]*a1; A[30]=A[15]*a2; A[31]=A[16]*a2; A[32]=A[17]*a2; A[33]=A[18]*a2;
}

// grid barrier: RELEASE arrive (flush prior writes once), RELAXED polls
// (no per-iteration cache ops -- the R4 mistake), single ACQUIRE at exit
// (invalidate stale L1/L2 once before next phase's reads).
__device__ __forceinline__ void gbar(int* bar, int idx) {
    __syncthreads();
    if (threadIdx.x == 0) {
        __hip_atomic_fetch_add(&bar[idx], 1, __ATOMIC_RELEASE, AG);
        while (__hip_atomic_load(&bar[idx], __ATOMIC_RELAXED, AG) < (int)gridDim.x)
            __builtin_amdgcn_s_sleep(8);
        (void)__hip_atomic_load(&bar[idx], __ATOMIC_ACQUIRE, AG);
    }
    __syncthreads();
}

__global__ __launch_bounds__(256) void fused_dam(
        const float* __restrict__ x,   const float* __restrict__ pew1,
        const float* __restrict__ pew2,
        const float* __restrict__ ew,  const float* __restrict__ eb,
        const float* __restrict__ g1,  const float* __restrict__ b1,
        const float* __restrict__ qpw, const float* __restrict__ ppw,
        const float* __restrict__ ppb, const float* __restrict__ rw,
        const float* __restrict__ rb,  const float* __restrict__ g2,
        const float* __restrict__ b2,  const float* __restrict__ qsw,
        const float* __restrict__ psw, const float* __restrict__ psb,
        const float* __restrict__ pdw1,const float* __restrict__ pdw2,
        float* __restrict__ ws, float* __restrict__ out) {
    __shared__ float smem[4608];
    const int b = blockIdx.x, tid = threadIdx.x;

    float* pos  = ws + W_POS;
    float* sn   = ws + W_SN;
    float* MT   = ws + W_MT;
    float* outs = ws + W_OUTS;
    float* pn   = ws + W_PN;
    float* pb   = ws + W_PB;
    float* qkvp = ws + W_QKV;
    float* op   = ws + W_OP;
    float* outp = ws + W_OUTP;
    float* mom  = ws + W_MOM;
    int*   bar  = (int*)(ws + W_BAR);

    // ================= P1: front conv+LN | MT | zero+warm =================
    if (b < 16) {
        float (*t1l)[8][64] = (float(*)[8][64])smem;
        int y0 = b * 4;
        for (int i = tid; i < 1536; i += 256) {
            int c = i >> 9, rr = (i >> 6) & 7, xx = i & 63;
            int yg = y0 - 2 + rr;
            float v = 0.f;
            if (yg >= 0 && yg < 64) v = gelu_exact(conv3_tap(x, pew1, c, yg, xx));
            t1l[c][rr][xx] = v;
        }
        __syncthreads();
        int n = b*256 + tid;
        int yl = tid >> 6, xx = tid & 63;
        int yg = y0 + yl;
        float p[3];
#pragma unroll
        for (int o = 0; o < 3; ++o) {
            float acc = 0.f;
#pragma unroll
            for (int ci = 0; ci < 3; ++ci) {
#pragma unroll
                for (int dy = 0; dy < 3; ++dy) {
                    int yy = yg + dy - 1;
                    if (yy < 0 || yy >= 64) continue;
                    int rl = yl + dy + 1;
#pragma unroll
                    for (int dx = 0; dx < 3; ++dx) {
                        int xc = xx + dx - 1;
                        if (xc < 0 || xc >= 64) continue;
                        acc = fmaf(t1l[ci][rl][xc], pew2[o*27 + ci*9 + dy*3 + dx], acc);
                    }
                }
            }
            p[o] = acc;
        }
        float mu = (p[0] + p[1] + p[2]) * (1.f/3.f);
        float d0 = p[0]-mu, d1 = p[1]-mu, d2 = p[2]-mu;
        float r = rsqrtf((d0*d0 + d1*d1 + d2*d2) * (1.f/3.f) + 1e-5f);
        pos[n] = p[0]; pos[NPIX+n] = p[1]; pos[2*NPIX+n] = p[2];
        sn[n]        = d0*r*g2[0] + b2[0];
        sn[NPIX+n]   = d1*r*g2[1] + b2[1];
        sn[2*NPIX+n] = d2*r*g2[2] + b2[2];
    } else if (b == 16) {
        if (tid < 144) {
            int isT = tid >= 72;
            int u = isT ? tid - 72 : tid;
            int h = u / 9, i = (u % 9) / 3, j = u % 3;
            float acc = 0.f;
            if (!isT) {   // M_h = Wq_h Wk_h^T / sqrt(32)
                const float* wq = qsw + i*768 + h*32;
                const float* wk = qsw + j*768 + 256 + h*32;
#pragma unroll
                for (int d = 0; d < 32; ++d) acc = fmaf(wq[d], wk[d], acc);
                acc *= 0.17677669529663687f;
            } else {      // T_h = Wv_h Pr_h
                const float* wv = qsw + i*768 + 512 + h*32;
#pragma unroll
                for (int d = 0; d < 32; ++d) acc = fmaf(wv[d], psw[(h*32 + d)*3 + j], acc);
            }
            MT[tid] = acc;
        }
    } else {
        // zero accumulators with agent-scope stores + warm L3 with weights
        int gid = (b - 17)*256 + tid;                 // 0..61183
        if (gid < NZERO)
            __hip_atomic_store(ws + W_PB + gid, 0.0f, __ATOMIC_RELAXED, AG);
        float acc = 0.f;
        for (int i = gid; i < 147456; i += 61184) { float4 v = ((const float4*)ew)[i];  acc += v.x+v.y+v.z+v.w; }
        for (int i = gid; i < 147456; i += 61184) { float4 v = ((const float4*)qpw)[i]; acc += v.x+v.y+v.z+v.w; }
        for (int i = gid; i < 49152;  i += 61184) { float4 v = ((const float4*)ppw)[i]; acc += v.x+v.y+v.z+v.w; }
        for (int i = gid; i < 147456; i += 61184) { float4 v = ((const float4*)rw)[i];  acc += v.x+v.y+v.z+v.w; }
        asm volatile("" :: "v"(acc));
    }
    gbar(bar, 0);

    // ====== P2: patch embed (96 blk, k-slice 24) | moments (16 blk) ========
    if (b < 96) {
        int och = b % 3, ks = b / 3;       // 32 k-splits of 24
        int k0 = ks * 24;
        float* pv = smem;                  // [16][24]
        for (int idx = tid; idx < 384; idx += 256) {
            int t = idx / 24, k = idx % 24;
            int kk = k0 + k;
            int cc = kk >> 8, pp = (kk >> 4) & 15, q = kk & 15;
            int hp = t >> 2, wp = t & 3;
            pv[idx] = pos[cc*NPIX + (hp*16 + pp)*64 + wp*16 + q];
        }
        __syncthreads();
        int o = och*256 + tid;
        float4 w4[6];
        const float4* wr = (const float4*)(ew + o*768 + k0);
#pragma unroll
        for (int i = 0; i < 6; ++i) w4[i] = wr[i];
        float acc[16];
#pragma unroll
        for (int t = 0; t < 16; ++t) acc[t] = 0.f;
#pragma unroll
        for (int i = 0; i < 6; ++i) {
#pragma unroll
            for (int t = 0; t < 16; ++t) {
                const float* p4 = &pv[t*24 + i*4];
                acc[t] = fmaf(w4[i].x, p4[0], acc[t]);
                acc[t] = fmaf(w4[i].y, p4[1], acc[t]);
                acc[t] = fmaf(w4[i].z, p4[2], acc[t]);
                acc[t] = fmaf(w4[i].w, p4[3], acc[t]);
            }
        }
#pragma unroll
        for (int t = 0; t < 16; ++t) atomicAdd(&pb[t*768 + o], acc[t]);
    } else if (b < 112) {
        int n = (b - 96)*256 + tid;
        float B[34];
        build34(sn[n], sn[NPIX+n], sn[2*NPIX+n], B);
        int lane = tid & 63, wid = tid >> 6;
#pragma unroll
        for (int u = 0; u < 34; ++u) {
            float t = B[u];
#pragma unroll
            for (int o = 1; o <= 32; o <<= 1) t += __shfl_xor(t, o);
            if (lane == 0) smem[wid*34 + u] = t;
        }
        __syncthreads();
        if (tid < 34)
            atomicAdd(&mom[tid], smem[tid] + smem[34+tid] + smem[68+tid] + smem[102+tid]);
    }
    gbar(bar, 1);

    // ================= P3: LN1 (16 blk) | pixel-attn poly eval (16 blk) ====
    if (b < 16) {
        int t = b;
        int base = t*768 + tid*3;
        float v0 = pb[base] + eb[tid*3], v1 = pb[base+1] + eb[tid*3+1],
              v2 = pb[base+2] + eb[tid*3+2];
        float s = v0+v1+v2, s2 = v0*v0+v1*v1+v2*v2;
#pragma unroll
        for (int o = 1; o <= 32; o <<= 1) { s += __shfl_xor(s, o); s2 += __shfl_xor(s2, o); }
        int wid = tid >> 6;
        if ((tid & 63) == 0) { smem[wid] = s; smem[4+wid] = s2; }
        __syncthreads();
        if (tid == 0) {
            float S = smem[0]+smem[1]+smem[2]+smem[3];
            float S2 = smem[4]+smem[5]+smem[6]+smem[7];
            float mu = S * (1.f/768.f);
            smem[8] = mu;
            smem[9] = rsqrtf(fmaxf(S2 * (1.f/768.f) - mu*mu, 0.f) + 1e-5f);
        }
        __syncthreads();
        float mu = smem[8], rs = smem[9];
        pn[base]   = (v0-mu)*rs*g1[tid*3]   + b1[tid*3];
        pn[base+1] = (v1-mu)*rs*g1[tid*3+1] + b1[tid*3+1];
        pn[base+2] = (v2-mu)*rs*g1[tid*3+2] + b1[tid*3+2];
    } else if (b < 32) {
        float* evmt = smem;          // 144
        float* evDW = smem + 144;    // 34
        float* evNW = smem + 180;    // 60  (3 x 20)
        if (tid < 144) evmt[tid] = MT[tid];
        if (tid < 34) {
            float c;
            if (tid < 3) c = 1.f;
            else if (tid < 9)  c = dC2[tid-3]  * 0.5f;
            else if (tid < 19) c = dC3[tid-9]  * (1.f/6.f);
            else               c = dC4[tid-19] * (1.f/24.f);
            evDW[tid] = c * mom[tid];
        }
        if (tid >= 192 && tid < 252) {
            int q = tid - 192; int j = q / 20, u = q % 20;
            float val;
            if (u == 0)       val = mom[j];
            else if (u < 4)   val = mom[3  + dT12[(u-1)*3 + j]];
            else if (u < 10)  val = (dC2[u-4]  * 0.5f)      * mom[9  + dT23[(u-4)*3 + j]];
            else              val = (dC3[u-10] * (1.f/6.f)) * mom[19 + dT34[(u-10)*3 + j]];
            evNW[j*20 + u] = val;
        }
        __syncthreads();
        int n = (b-16)*256 + tid;
        float x0 = sn[n], x1 = sn[NPIX+n], x2 = sn[2*NPIX+n];
        float o0 = 0.f, o1 = 0.f, o2 = 0.f;
        for (int h = 0; h < 8; ++h) {
            const float* M = &evmt[h*9];
            float a0 = x0*M[0] + x1*M[3] + x2*M[6];
            float a1 = x0*M[1] + x1*M[4] + x2*M[7];
            float a2 = x0*M[2] + x1*M[5] + x2*M[8];
            float A[34];
            build34(a0, a1, a2, A);
            float den = 4096.f;
#pragma unroll
            for (int u = 0; u < 34; ++u) den = fmaf(A[u], evDW[u], den);
            float num[3];
#pragma unroll
            for (int j = 0; j < 3; ++j) {
                float s = evNW[j*20];
#pragma unroll
                for (int u = 0; u < 19; ++u) s = fmaf(A[u], evNW[j*20 + 1 + u], s);
                num[j] = s;
            }
            float ir = 1.f / den;
            float r0 = num[0]*ir, r1 = num[1]*ir, r2 = num[2]*ir;
            const float* T = &evmt[72 + h*9];
            o0 += r0*T[0] + r1*T[3] + r2*T[6];
            o1 += r0*T[1] + r1*T[4] + r2*T[7];
            o2 += r0*T[2] + r1*T[5] + r2*T[8];
        }
        outs[n]        = o0 + psb[0];
        outs[NPIX+n]   = o1 + psb[1];
        outs[2*NPIX+n] = o2 + psb[2];
    }
    gbar(bar, 2);

    // ================= P4: qkv_patch GEMM (96 blk, k-slice 24) =============
    if (b < 96) {
        int och = b % 3, ks = b / 3;
        int k0 = ks * 24;
        float* ps = smem;                // [16][24]
        for (int idx = tid; idx < 384; idx += 256) {
            int t = idx / 24, k = idx % 24;
            ps[idx] = pn[t*768 + k0 + k];
        }
        __syncthreads();
        int o = och*256 + tid;
        float acc[16];
#pragma unroll
        for (int t = 0; t < 16; ++t) acc[t] = 0.f;
#pragma unroll
        for (int k = 0; k < 24; ++k) {
            float w = qpw[(k0 + k)*768 + o];
#pragma unroll
            for (int t = 0; t < 16; ++t) acc[t] = fmaf(ps[t*24 + k], w, acc[t]);
        }
#pragma unroll
        for (int t = 0; t < 16; ++t) atomicAdd(&qkvp[t*768 + o], acc[t]);
    }
    gbar(bar, 3);

    // ====== P5: patch attention (1 head/blk) + proj k-slice (24 blk) =======
    if (b < 24) {
        int och = b % 3, h = b / 3;
        float* qsl = smem;            // [16][32]
        float* ksl = smem + 512;
        float* vsl = smem + 1024;
        float* scl = smem + 1536;     // [16][16]
        float* att = smem + 1792;     // [16][32]
        for (int idx = tid; idx < 512; idx += 256) {
            int t = idx >> 5, j = idx & 31;
            qsl[idx] = qkvp[t*768 + h*32 + j];
            ksl[idx] = qkvp[t*768 + 256 + h*32 + j];
            vsl[idx] = qkvp[t*768 + 512 + h*32 + j];
        }
        __syncthreads();
        {
            int nn = tid >> 4, m = tid & 15;
            float d = 0.f;
            const float* q = &qsl[nn*32];
            const float* k = &ksl[m*32];
#pragma unroll
            for (int dd = 0; dd < 32; ++dd) d = fmaf(q[dd], k[dd], d);
            scl[tid] = d * 0.17677669529663687f;
        }
        __syncthreads();
        if (tid < 16) {
            float* row = &scl[tid*16];
            float mx = row[0];
#pragma unroll
            for (int m = 1; m < 16; ++m) mx = fmaxf(mx, row[m]);
            float s = 0.f;
#pragma unroll
            for (int m = 0; m < 16; ++m) { float e = expf(row[m]-mx); row[m] = e; s += e; }
            float inv = 1.f / s;
#pragma unroll
            for (int m = 0; m < 16; ++m) row[m] *= inv;
        }
        __syncthreads();
#pragma unroll
        for (int r = 0; r < 2; ++r) {
            int idx = tid + r*256;
            int nn = idx >> 5, d = idx & 31;
            float a = 0.f;
#pragma unroll
            for (int m = 0; m < 16; ++m)
                a = fmaf(scl[nn*16 + m], vsl[m*32 + d], a);
            att[nn*32 + d] = a;
        }
        __syncthreads();
        int o = och*256 + tid;
        float acc[16];
#pragma unroll
        for (int t = 0; t < 16; ++t) acc[t] = 0.f;
#pragma unroll
        for (int k = 0; k < 32; ++k) {
            float w = ppw[(h*32 + k)*768 + o];
#pragma unroll
            for (int t = 0; t < 16; ++t) acc[t] = fmaf(att[t*32 + k], w, acc[t]);
        }
#pragma unroll
        for (int t = 0; t < 16; ++t) atomicAdd(&op[t*768 + o], acc[t]);
    }
    gbar(bar, 4);

    // ================= P6: recon conv-transpose (96 blk, c-slice 24) =======
    if (b < 96) {
        int dch = b % 3, cs = b / 3;
        int c0 = cs * 24;
        float* os_ = smem;             // [16][24]
        for (int idx = tid; idx < 384; idx += 256) {
            int t = idx / 24, k = idx % 24;
            os_[idx] = op[t*768 + c0 + k] + ppb[c0 + k];
        }
        __syncthreads();
        int dij = dch*256 + tid;
        float acc[16];
#pragma unroll
        for (int t = 0; t < 16; ++t) acc[t] = 0.f;
#pragma unroll
        for (int k = 0; k < 24; ++k) {
            float w = rw[(c0 + k)*768 + dij];
#pragma unroll
            for (int t = 0; t < 16; ++t) acc[t] = fmaf(os_[t*24 + k], w, acc[t]);
        }
        int d = dij >> 8, i = (dij >> 4) & 15, j = dij & 15;
#pragma unroll
        for (int t = 0; t < 16; ++t) {
            int hp = t >> 2, wp = t & 3;
            atomicAdd(&outp[d*NPIX + (hp*16 + i)*64 + wp*16 + j], acc[t]);
        }
    }
    gbar(bar, 5);

    // ================= P7: combine + final convs ===========================
    if (b < 16) {
        float (*t2l)[8][64] = (float(*)[8][64])smem;
        int y0 = b * 4;
        for (int i = tid; i < 1536; i += 256) {
            int c = i >> 9, rr = (i >> 6) & 7, xx = i & 63;
            int yg = y0 - 2 + rr;
            float v = 0.f;
            if (yg >= 0 && yg < 64) {
                float acc = 0.f;
#pragma unroll
                for (int ci = 0; ci < 3; ++ci) {
                    float bias = rb[ci];
#pragma unroll
                    for (int dy = 0; dy < 3; ++dy) {
                        int yy = yg + dy - 1;
                        if (yy < 0 || yy >= 64) continue;
#pragma unroll
                        for (int dx = 0; dx < 3; ++dx) {
                            int xc = xx + dx - 1;
                            if (xc < 0 || xc >= 64) continue;
                            float cb = outp[ci*NPIX + yy*64 + xc] + bias
                                     + outs[ci*NPIX + yy*64 + xc];
                            acc = fmaf(cb, pdw1[c*27 + ci*9 + dy*3 + dx], acc);
                        }
                    }
                }
                v = gelu_exact(acc);
            }
            t2l[c][rr][xx] = v;
        }
        __syncthreads();
        int yl = tid >> 6, xx = tid & 63;
        int yg = y0 + yl;
#pragma unroll
        for (int o = 0; o < 3; ++o) {
            float acc = 0.f;
#pragma unroll
            for (int ci = 0; ci < 3; ++ci) {
#pragma unroll
                for (int dy = 0; dy < 3; ++dy) {
                    int yy = yg + dy - 1;
                    if (yy < 0 || yy >= 64) continue;
                    int rl = yl + dy + 1;
#pragma unroll
                    for (int dx = 0; dx < 3; ++dx) {
                        int xc = xx + dx - 1;
                        if (xc < 0 || xc >= 64) continue;
                        acc = fmaf(t2l[ci][rl][xc], pdw2[o*27 + ci*9 + dy*3 + dx], acc);
                    }
                }
            }
            out[o*NPIX + yg*64 + xx] = acc;
        }
    }
}

extern "C" void kernel_launch(void* const* d_in, const int* in_sizes, int n_in,
                              void* d_out, int out_size, void* d_ws, size_t ws_size,
                              hipStream_t stream) {
    (void)in_sizes; (void)n_in; (void)out_size; (void)ws_size;
    const float* x    = (const float*)d_in[0];
    const float* pew1 = (const float*)d_in[1];
    const float* pew2 = (const float*)d_in[2];
    const float* ew   = (const float*)d_in[3];
    const float* eb   = (const float*)d_in[4];
    const float* g1   = (const float*)d_in[5];
    const float* b1   = (const float*)d_in[6];
    const float* qpw  = (const float*)d_in[7];
    const float* ppw  = (const float*)d_in[8];
    const float* ppb  = (const float*)d_in[9];
    const float* rw   = (const float*)d_in[10];
    const float* rb   = (const float*)d_in[11];
    const float* g2   = (const float*)d_in[12];
    const float* b2   = (const float*)d_in[13];
    const float* qsw  = (const float*)d_in[14];
    const float* psw  = (const float*)d_in[15];
    const float* psb  = (const float*)d_in[16];
    const float* pdw1 = (const float*)d_in[17];
    const float* pdw2 = (const float*)d_in[18];

    float* ws  = (float*)d_ws;
    float* out = (float*)d_out;

    hipMemsetAsync((char*)d_ws + (size_t)W_BAR*4, 0, 64, stream);
    fused_dam<<<dim3(256), dim3(256), 0, stream>>>(
        x, pew1, pew2, ew, eb, g1, b1, qpw, ppw, ppb, rw, rb, g2, b2,
        qsw, psw, psb, pdw1, pdw2, ws, out);
}